// Round 3
// baseline (2270.411 us; speedup 1.0000x reference)
//
#include <hip/hip_runtime.h>

typedef float f32x4 __attribute__((ext_vector_type(4)));
typedef int i32x8v __attribute__((ext_vector_type(8)));
typedef unsigned char uchar;
typedef long i64;

#define KEPS 1e-8f
#define BM 128
#define BN 128
#define BK 128   // fp8 bytes == elements; 8 K-iterations over D=1024

// ---------------- 1) row L2-normalize: fp32 norms + fp8 e4m3 copy -----------
__global__ __launch_bounds__(256) void k_normalize(
    const float* __restrict__ in, uchar* __restrict__ xq,
    float* __restrict__ norms, unsigned long long* __restrict__ best,
    float* __restrict__ psum, int D)
{
    const int row = blockIdx.x;
    const int t = threadIdx.x;
    const float4* inr = (const float4*)(in + (size_t)row * D);
    float4 v = inr[t];                       // D=1024 -> 256 float4
    float ss = v.x*v.x + v.y*v.y + v.z*v.z + v.w*v.w;
    for (int off = 32; off; off >>= 1) ss += __shfl_down(ss, off);
    __shared__ float red[4];
    const int lane = t & 63, wave = t >> 6;
    if (lane == 0) red[wave] = ss;
    __syncthreads();
    const float total = red[0] + red[1] + red[2] + red[3];
    const float nrm = sqrtf(total);
    const float inv = 1.0f / fmaxf(nrm, KEPS);
    unsigned r = 0;
    r = __builtin_amdgcn_cvt_pk_fp8_f32(v.x * inv, v.y * inv, r, 0);
    r = __builtin_amdgcn_cvt_pk_fp8_f32(v.z * inv, v.w * inv, r, 1);
    ((unsigned*)(xq + (size_t)row * D))[t] = r;
    if (t == 0) {
        norms[row] = nrm;
        best[row] = 0ull;                    // any real packed key beats 0
    }
    if (row < 256 && t == 1) psum[row * 16] = 0.0f;   // cache-line-padded partials
}

__device__ __forceinline__ unsigned long long pack_key(float v, unsigned idx)
{
    unsigned ub = __float_as_uint(v);
    ub = (ub & 0x80000000u) ? ~ub : (ub | 0x80000000u); // monotonic map
    return ((unsigned long long)ub << 32) | (unsigned long long)(~idx);
}

// ---------------- 2) x x^T triangular fp8 GEMM, MX-rate 16x16x128 MFMA ------
// BM=BN=128, BK=128 bytes, 4 waves in 2x2, each wave owns 64x64 as 4x4 of
// 16x16. mfma_scale_f32_16x16x128_f8f6f4 with unit scales (e8m0 0x7F = 2^0):
// 2x-rate MX pipe, numerically identical to plain fp8 (round-1 verified).
// WHY 16x16x128 (round-3 fix): the 32x32x64 variant's f32x16 C/D caused
// persistent accumulator spills (WRITE_SIZE 82MB -> 2.7-3.0GB scratch) even
// at (256,3) — tied-operand copies of 16-wide accs. The 16x16x128 C/D is
// f32x4: acc[4][4] footprint identical to the clean round-0 kernel (64 AGPR).
// This is also the config the measured MX ladder used (m148: 1628 TF).
// LDS: single 32 KiB buffer (m97/m148 structure), stage->barrier->compute->
// barrier; 3 blocks/CU via (256,3) gives cross-block latency hiding.
// Swizzle at 32B granularity: chunk32 ^= (row ^ row>>2) & 3, applied to the
// GLOBAL source column (LDS stays linear for global_load_lds). Each lane's
// 32B MFMA fragment is then CONTIGUOUS in LDS -> one i32x8v load = 2x
// ds_read_b128, no shuffle glue.
__global__ __launch_bounds__(256, 3) void k_gemm_argmax(
    const uchar* __restrict__ xq, unsigned long long* __restrict__ best,
    int T)
{
    // triangular mapping: p -> (by, bx), bx >= by
    const int p = blockIdx.x;
    const float tf = (float)T + 0.5f;
    int by = (int)(tf - sqrtf(tf * tf - 2.0f * (float)p));
    while (by > 0 && p < by * T - by * (by - 1) / 2) --by;
    while (p >= (by + 1) * T - (by + 1) * by / 2) ++by;
    const int bx = by + (p - (by * T - by * (by - 1) / 2));

    __shared__ __align__(1024) uchar lds[(BM + BN) * BK];   // 32 KiB, single buffer
    const int t    = threadIdx.x;
    const int lane = t & 63;
    const int wave = t >> 6;
    const int quad = lane >> 4;
    const int c16  = lane & 15;
    const int wrow = (wave >> 1) * 64;
    const int wcol = (wave & 1) * 64;
    const int m0   = by * BM;
    const int n0   = bx * BN;

    f32x4 acc[4][4] = {};

    // staging: thread t stores 16B at LDS row = rg*32 + (t>>3), chunk16 = t&7
    // (rg = 0..3 row-groups per 128-row panel). Global col pre-swizzled at
    // 32B granularity; psw(row) depends only on row&15 -> invariant to rg*32.
    const int row_s  = t >> 3;                 // 0..31
    const int c32_s  = (t & 7) >> 1;           // 32B chunk 0..3
    const int half_s = (t & 1) * 16;
    const int psw_s  = (row_s ^ (row_s >> 2)) & 3;
    const int gcol   = ((c32_s ^ psw_s) * 32) + half_s;   // byte col in row
    const uchar* aP = xq + (size_t)(m0 + row_s) * 1024 + gcol;
    const uchar* bP = xq + (size_t)(n0 + row_s) * 1024 + gcol;
    const int ldst = t * 16;

#define STAGE(koff)                                                                    \
    do {                                                                               \
        _Pragma("unroll")                                                              \
        for (int rg = 0; rg < 4; ++rg) {                                               \
            __builtin_amdgcn_global_load_lds(                                          \
                (const __attribute__((address_space(1))) void*)(aP + rg * 32768 + (koff)), \
                (__attribute__((address_space(3))) void*)(&lds[0] + rg * 4096 + ldst), \
                16, 0, 0);                                                             \
            __builtin_amdgcn_global_load_lds(                                          \
                (const __attribute__((address_space(1))) void*)(bP + rg * 32768 + (koff)), \
                (__attribute__((address_space(3))) void*)(&lds[16384] + rg * 4096 + ldst), \
                16, 0, 0);                                                             \
        }                                                                              \
    } while (0)

    STAGE(0);

    // lane-constant LDS read offsets.
    // A fragment (16x16x128): lane holds row (lane&15), k-bytes [32*quad, +32).
    // LDS row = wrow + i*16 + c16; psw(row) = (c16 ^ (c16>>2)) & 3 (multiples
    // of 16 drop out of both XOR terms). Swizzled 32B chunk = quad ^ psw.
    const int psw_r = (c16 ^ (c16 >> 2)) & 3;
    const int csw   = ((quad ^ psw_r) * 32);
    int aoff[4], boff[4];
    #pragma unroll
    for (int i = 0; i < 4; ++i) {
        aoff[i] = (wrow + i * 16 + c16) * 128 + csw;
        boff[i] = 16384 + (wcol + i * 16 + c16) * 128 + csw;
    }

    #pragma unroll
    for (int kt = 0; kt < 8; ++kt) {
        __syncthreads();                       // drains staged loads (vmcnt)
        const uchar* L = &lds[0];
        i32x8v bf[4];
        #pragma unroll
        for (int j = 0; j < 4; ++j)
            bf[j] = *(const i32x8v*)(L + boff[j]);
        #pragma unroll
        for (int i = 0; i < 4; ++i) {
            const i32x8v af = *(const i32x8v*)(L + aoff[i]);
            #pragma unroll
            for (int j = 0; j < 4; ++j)
                acc[i][j] = __builtin_amdgcn_mfma_scale_f32_16x16x128_f8f6f4(
                    af, bf[j], acc[i][j], 0, 0, 0, 0x7F, 0, 0x7F);
        }
        __syncthreads();                       // all waves done reading tile
        if (kt < 7) STAGE((kt + 1) * BK);      // restage into same buffer
    }
#undef STAGE

    // ---- row-wise argmax (this wave's 64 rows, over its 64 cols) ----
    // C/D layout (shape-determined): col = lane&15, row = quad*4 + reg.
    #pragma unroll
    for (int i = 0; i < 4; ++i) {
        #pragma unroll
        for (int r = 0; r < 4; ++r) {
            const int grow = m0 + wrow + i * 16 + quad * 4 + r;
            float v = -3.0f; unsigned c = 0xFFFFFFFFu;
            #pragma unroll
            for (int j = 0; j < 4; ++j) {
                const int col = n0 + wcol + j * 16 + c16;
                const float val = acc[i][j][r];
                if (col != grow && (val > v || (val == v && (unsigned)col < c))) {
                    v = val; c = (unsigned)col;
                }
            }
            // reduce across the quad's 16 lanes (one row lives in one quad)
            for (int off = 8; off; off >>= 1) {
                const float    ov = __shfl_xor(v, off);
                const unsigned oc = (unsigned)__shfl_xor((int)c, off);
                if (ov > v || (ov == v && oc < c)) { v = ov; c = oc; }
            }
            if (c16 == 0) atomicMax(best + grow, pack_key(v, c));
        }
    }

    // ---- col-wise argmax (off-diagonal blocks only) ----
    if (bx != by) {
        #pragma unroll
        for (int j = 0; j < 4; ++j) {
            const int gcol2 = n0 + wcol + j * 16 + c16;
            float v = -3.0f; unsigned c = 0xFFFFFFFFu;
            #pragma unroll
            for (int i = 0; i < 4; ++i) {
                #pragma unroll
                for (int r = 0; r < 4; ++r) {
                    const int grow = m0 + wrow + i * 16 + quad * 4 + r;
                    const float val = acc[i][j][r];
                    if (val > v || (val == v && (unsigned)grow < c)) {
                        v = val; c = (unsigned)grow;
                    }
                }
            }
            // reduce across the 4 quads (lanes sharing c16): xor 16, 32
            for (int off = 32; off >= 16; off >>= 1) {
                const float    ov = __shfl_xor(v, off);
                const unsigned oc = (unsigned)__shfl_xor((int)c, off);
                if (ov > v || (ov == v && oc < c)) { v = ov; c = oc; }
            }
            if (quad == 0) atomicMax(best + gcol2, pack_key(v, c));
        }
    }
}

// ---------------- 3) pairwise distance + log -> 256 padded partials ---------
__global__ __launch_bounds__(256) void k_dist(
    const float* __restrict__ in, const float* __restrict__ norms,
    const unsigned long long* __restrict__ best, float* __restrict__ psum, int D)
{
    const int row = blockIdx.x;
    const int t = threadIdx.x;
    const unsigned long long key = best[row];
    const int nb = (int)(~(unsigned)key);        // recover neighbor index
    const float invi = 1.0f / fmaxf(norms[row], KEPS);
    const float invj = 1.0f / fmaxf(norms[nb], KEPS);
    const float4* xi = (const float4*)(in + (size_t)row * D);
    const float4* xj = (const float4*)(in + (size_t)nb * D);
    const float4 a = xi[t], b = xj[t];
    const float dx = a.x * invi - b.x * invj + KEPS;
    const float dy = a.y * invi - b.y * invj + KEPS;
    const float dz = a.z * invi - b.z * invj + KEPS;
    const float dw = a.w * invi - b.w * invj + KEPS;
    float ss = dx*dx + dy*dy + dz*dz + dw*dw;
    for (int off = 32; off; off >>= 1) ss += __shfl_down(ss, off);
    __shared__ float red[4];
    const int lane = t & 63, wave = t >> 6;
    if (lane == 0) red[wave] = ss;
    __syncthreads();
    if (t == 0) {
        const float tot = red[0] + red[1] + red[2] + red[3];
        // scatter over 256 cache-line-padded slots: 64 atomics/slot, no hotspot
        atomicAdd(psum + (row & 255) * 16, logf(sqrtf(tot) + KEPS));
    }
}

// ---------------- 4) finalize: reduce 256 partials --------------------------
__global__ void k_final(const float* __restrict__ psum, float* __restrict__ out, float invN)
{
    const int t = threadIdx.x;                   // 64 threads
    float s = psum[t * 16] + psum[(t + 64) * 16]
            + psum[(t + 128) * 16] + psum[(t + 192) * 16];
    for (int off = 32; off; off >>= 1) s += __shfl_down(s, off);
    if (t == 0) out[0] = -s * invN;
}

extern "C" void kernel_launch(void* const* d_in, const int* in_sizes, int n_in,
                              void* d_out, int out_size, void* d_ws, size_t ws_size,
                              hipStream_t stream)
{
    const float* in = (const float*)d_in[0];
    const int D = 1024;
    const int N = in_sizes[0] / D;               // 16384

    char* ws = (char*)d_ws;
    uchar* xq = (uchar*)ws;                                      // N*D = 16 MiB
    size_t off = (size_t)N * D;
    float* norms = (float*)(ws + off);           off += (size_t)N * 4;
    unsigned long long* best = (unsigned long long*)(ws + off); off += (size_t)N * 8;
    float* psum = (float*)(ws + off);            // 256 slots x 16 floats
    float* out = (float*)d_out;

    k_normalize<<<N, 256, 0, stream>>>(in, xq, norms, best, psum, D);
    const int T = N / BM;                        // 128 tiles per dim
    const int P = T * (T + 1) / 2;               // 8256 upper-tri blocks
    k_gemm_argmax<<<P, 256, 0, stream>>>(xq, best, T);
    k_dist<<<N, 256, 0, stream>>>(in, norms, best, psum, D);
    k_final<<<1, 64, 0, stream>>>(psum, out, 1.0f / (float)N);
}

// Round 4
// 848.203 us; speedup vs baseline: 2.6767x; 2.6767x over previous
//
#include <hip/hip_runtime.h>

typedef float f32x4 __attribute__((ext_vector_type(4)));
typedef int i32x8v __attribute__((ext_vector_type(8)));
typedef unsigned char uchar;
typedef long i64;

#define KEPS 1e-8f
#define BM 128
#define BN 128
#define BK 128   // fp8 bytes == elements; 8 K-iterations over D=1024

// ---------------- 1) row L2-normalize: fp32 norms + fp8 e4m3 copy -----------
__global__ __launch_bounds__(256) void k_normalize(
    const float* __restrict__ in, uchar* __restrict__ xq,
    float* __restrict__ norms, unsigned long long* __restrict__ best,
    float* __restrict__ psum, int D)
{
    const int row = blockIdx.x;
    const int t = threadIdx.x;
    const float4* inr = (const float4*)(in + (size_t)row * D);
    float4 v = inr[t];                       // D=1024 -> 256 float4
    float ss = v.x*v.x + v.y*v.y + v.z*v.z + v.w*v.w;
    for (int off = 32; off; off >>= 1) ss += __shfl_down(ss, off);
    __shared__ float red[4];
    const int lane = t & 63, wave = t >> 6;
    if (lane == 0) red[wave] = ss;
    __syncthreads();
    const float total = red[0] + red[1] + red[2] + red[3];
    const float nrm = sqrtf(total);
    const float inv = 1.0f / fmaxf(nrm, KEPS);
    unsigned r = 0;
    r = __builtin_amdgcn_cvt_pk_fp8_f32(v.x * inv, v.y * inv, r, 0);
    r = __builtin_amdgcn_cvt_pk_fp8_f32(v.z * inv, v.w * inv, r, 1);
    ((unsigned*)(xq + (size_t)row * D))[t] = r;
    if (t == 0) {
        norms[row] = nrm;
        best[row] = 0ull;                    // any real packed key beats 0
    }
    if (row < 256 && t == 1) psum[row * 16] = 0.0f;   // cache-line-padded partials
}

__device__ __forceinline__ unsigned long long pack_key(float v, unsigned idx)
{
    unsigned ub = __float_as_uint(v);
    ub = (ub & 0x80000000u) ? ~ub : (ub | 0x80000000u); // monotonic map
    return ((unsigned long long)ub << 32) | (unsigned long long)(~idx);
}

// ---------------- 2) x x^T triangular fp8 GEMM, MX-rate 16x16x128 MFMA ------
// BM=BN=128, BK=128 bytes, 4 waves in 2x2, each wave owns 64x64 as 4x4 of
// 16x16. mfma_scale_f32_16x16x128_f8f6f4 with unit scales (e8m0 0x7F = 2^0):
// 2x-rate MX pipe, numerically identical to plain fp8 (rounds 1-3 verified).
// ROUND-4 FIX: NO min-waves launch_bounds. Rounds 1-3 all spilled the MFMA
// OPERAND fragments (~1.35 KB/thread scratch writes = 40 operand dwords x
// 8 K-steps): gfx950 splits the granted unified budget ~50/50 into arch
// VGPRs / AGPRs (reported VGPR 64 @ (256,4), 84 @ (256,3)), starving the
// arch side (demand ~100: af 8 + bf[4] 32 + staging addrs + misc). With no
// min-waves cap the allocator takes ~170-230 regs with a fitting
// accum_offset -> no spill, ~2 blocks/CU — exactly the regime where the
// identically-structured m148 MX-fp8 kernel measured 1628 TF (1.78x the
// non-MX analog of our round-0 860 TF).
// LDS: single 32 KiB buffer (m97/m148 structure): STAGE; {barrier; compute;
// barrier; STAGE next}. Swizzle at 32B granularity applied to the GLOBAL
// source column (LDS stays linear for global_load_lds); each lane's 32B
// fragment is contiguous in LDS -> one i32x8v load = 2x ds_read_b128.
__global__ __launch_bounds__(256) void k_gemm_argmax(
    const uchar* __restrict__ xq, unsigned long long* __restrict__ best,
    int T)
{
    // triangular mapping: p -> (by, bx), bx >= by
    const int p = blockIdx.x;
    const float tf = (float)T + 0.5f;
    int by = (int)(tf - sqrtf(tf * tf - 2.0f * (float)p));
    while (by > 0 && p < by * T - by * (by - 1) / 2) --by;
    while (p >= (by + 1) * T - (by + 1) * by / 2) ++by;
    const int bx = by + (p - (by * T - by * (by - 1) / 2));

    __shared__ __align__(1024) uchar lds[(BM + BN) * BK];   // 32 KiB, single buffer
    const int t    = threadIdx.x;
    const int lane = t & 63;
    const int wave = t >> 6;
    const int quad = lane >> 4;
    const int c16  = lane & 15;
    const int wrow = (wave >> 1) * 64;
    const int wcol = (wave & 1) * 64;
    const int m0   = by * BM;
    const int n0   = bx * BN;

    f32x4 acc[4][4] = {};

    // staging: thread t stores 16B at LDS row = rg*32 + (t>>3), chunk16 = t&7
    // (rg = 0..3 row-groups per 128-row panel). Global col pre-swizzled at
    // 32B granularity; psw(row) depends only on row&15 -> invariant to rg*32.
    const int row_s  = t >> 3;                 // 0..31
    const int c32_s  = (t & 7) >> 1;           // 32B chunk 0..3
    const int half_s = (t & 1) * 16;
    const int psw_s  = (row_s ^ (row_s >> 2)) & 3;
    const int gcol   = ((c32_s ^ psw_s) * 32) + half_s;   // byte col in row
    const uchar* aP = xq + (size_t)(m0 + row_s) * 1024 + gcol;
    const uchar* bP = xq + (size_t)(n0 + row_s) * 1024 + gcol;
    const int ldst = t * 16;

#define STAGE(koff)                                                                    \
    do {                                                                               \
        _Pragma("unroll")                                                              \
        for (int rg = 0; rg < 4; ++rg) {                                               \
            __builtin_amdgcn_global_load_lds(                                          \
                (const __attribute__((address_space(1))) void*)(aP + rg * 32768 + (koff)), \
                (__attribute__((address_space(3))) void*)(&lds[0] + rg * 4096 + ldst), \
                16, 0, 0);                                                             \
            __builtin_amdgcn_global_load_lds(                                          \
                (const __attribute__((address_space(1))) void*)(bP + rg * 32768 + (koff)), \
                (__attribute__((address_space(3))) void*)(&lds[16384] + rg * 4096 + ldst), \
                16, 0, 0);                                                             \
        }                                                                              \
    } while (0)

    STAGE(0);

    // lane-constant LDS read offsets.
    // A fragment (16x16x128): lane holds row (lane&15), k-bytes [32*quad, +32).
    // LDS row = wrow + i*16 + c16; psw(row) = (c16 ^ (c16>>2)) & 3 (multiples
    // of 16 drop out of both XOR terms). Swizzled 32B chunk = quad ^ psw.
    const int psw_r = (c16 ^ (c16 >> 2)) & 3;
    const int csw   = ((quad ^ psw_r) * 32);
    int aoff[4], boff[4];
    #pragma unroll
    for (int i = 0; i < 4; ++i) {
        aoff[i] = (wrow + i * 16 + c16) * 128 + csw;
        boff[i] = 16384 + (wcol + i * 16 + c16) * 128 + csw;
    }

    #pragma unroll
    for (int kt = 0; kt < 8; ++kt) {
        __syncthreads();                       // drains staged loads (vmcnt)
        const uchar* L = &lds[0];
        i32x8v bf[4];
        #pragma unroll
        for (int j = 0; j < 4; ++j)
            bf[j] = *(const i32x8v*)(L + boff[j]);
        #pragma unroll
        for (int i = 0; i < 4; ++i) {
            const i32x8v af = *(const i32x8v*)(L + aoff[i]);
            #pragma unroll
            for (int j = 0; j < 4; ++j)
                acc[i][j] = __builtin_amdgcn_mfma_scale_f32_16x16x128_f8f6f4(
                    af, bf[j], acc[i][j], 0, 0, 0, 0x7F, 0, 0x7F);
        }
        __syncthreads();                       // all waves done reading tile
        if (kt < 7) STAGE((kt + 1) * BK);      // restage into same buffer
    }
#undef STAGE

    // ---- row-wise argmax (this wave's 64 rows, over its 64 cols) ----
    // C/D layout (shape-determined): col = lane&15, row = quad*4 + reg.
    #pragma unroll
    for (int i = 0; i < 4; ++i) {
        #pragma unroll
        for (int r = 0; r < 4; ++r) {
            const int grow = m0 + wrow + i * 16 + quad * 4 + r;
            float v = -3.0f; unsigned c = 0xFFFFFFFFu;
            #pragma unroll
            for (int j = 0; j < 4; ++j) {
                const int col = n0 + wcol + j * 16 + c16;
                const float val = acc[i][j][r];
                if (col != grow && (val > v || (val == v && (unsigned)col < c))) {
                    v = val; c = (unsigned)col;
                }
            }
            // reduce across the quad's 16 lanes (one row lives in one quad)
            for (int off = 8; off; off >>= 1) {
                const float    ov = __shfl_xor(v, off);
                const unsigned oc = (unsigned)__shfl_xor((int)c, off);
                if (ov > v || (ov == v && oc < c)) { v = ov; c = oc; }
            }
            if (c16 == 0) atomicMax(best + grow, pack_key(v, c));
        }
    }

    // ---- col-wise argmax (off-diagonal blocks only) ----
    if (bx != by) {
        #pragma unroll
        for (int j = 0; j < 4; ++j) {
            const int gcol2 = n0 + wcol + j * 16 + c16;
            float v = -3.0f; unsigned c = 0xFFFFFFFFu;
            #pragma unroll
            for (int i = 0; i < 4; ++i) {
                #pragma unroll
                for (int r = 0; r < 4; ++r) {
                    const int grow = m0 + wrow + i * 16 + quad * 4 + r;
                    const float val = acc[i][j][r];
                    if (val > v || (val == v && (unsigned)grow < c)) {
                        v = val; c = (unsigned)grow;
                    }
                }
            }
            // reduce across the 4 quads (lanes sharing c16): xor 16, 32
            for (int off = 32; off >= 16; off >>= 1) {
                const float    ov = __shfl_xor(v, off);
                const unsigned oc = (unsigned)__shfl_xor((int)c, off);
                if (ov > v || (ov == v && oc < c)) { v = ov; c = oc; }
            }
            if (quad == 0) atomicMax(best + gcol2, pack_key(v, c));
        }
    }
}

// ---------------- 3) pairwise distance + log -> 256 padded partials ---------
__global__ __launch_bounds__(256) void k_dist(
    const float* __restrict__ in, const float* __restrict__ norms,
    const unsigned long long* __restrict__ best, float* __restrict__ psum, int D)
{
    const int row = blockIdx.x;
    const int t = threadIdx.x;
    const unsigned long long key = best[row];
    const int nb = (int)(~(unsigned)key);        // recover neighbor index
    const float invi = 1.0f / fmaxf(norms[row], KEPS);
    const float invj = 1.0f / fmaxf(norms[nb], KEPS);
    const float4* xi = (const float4*)(in + (size_t)row * D);
    const float4* xj = (const float4*)(in + (size_t)nb * D);
    const float4 a = xi[t], b = xj[t];
    const float dx = a.x * invi - b.x * invj + KEPS;
    const float dy = a.y * invi - b.y * invj + KEPS;
    const float dz = a.z * invi - b.z * invj + KEPS;
    const float dw = a.w * invi - b.w * invj + KEPS;
    float ss = dx*dx + dy*dy + dz*dz + dw*dw;
    for (int off = 32; off; off >>= 1) ss += __shfl_down(ss, off);
    __shared__ float red[4];
    const int lane = t & 63, wave = t >> 6;
    if (lane == 0) red[wave] = ss;
    __syncthreads();
    if (t == 0) {
        const float tot = red[0] + red[1] + red[2] + red[3];
        // scatter over 256 cache-line-padded slots: 64 atomics/slot, no hotspot
        atomicAdd(psum + (row & 255) * 16, logf(sqrtf(tot) + KEPS));
    }
}

// ---------------- 4) finalize: reduce 256 partials --------------------------
__global__ void k_final(const float* __restrict__ psum, float* __restrict__ out, float invN)
{
    const int t = threadIdx.x;                   // 64 threads
    float s = psum[t * 16] + psum[(t + 64) * 16]
            + psum[(t + 128) * 16] + psum[(t + 192) * 16];
    for (int off = 32; off; off >>= 1) s += __shfl_down(s, off);
    if (t == 0) out[0] = -s * invN;
}

extern "C" void kernel_launch(void* const* d_in, const int* in_sizes, int n_in,
                              void* d_out, int out_size, void* d_ws, size_t ws_size,
                              hipStream_t stream)
{
    const float* in = (const float*)d_in[0];
    const int D = 1024;
    const int N = in_sizes[0] / D;               // 16384

    char* ws = (char*)d_ws;
    uchar* xq = (uchar*)ws;                                      // N*D = 16 MiB
    size_t off = (size_t)N * D;
    float* norms = (float*)(ws + off);           off += (size_t)N * 4;
    unsigned long long* best = (unsigned long long*)(ws + off); off += (size_t)N * 8;
    float* psum = (float*)(ws + off);            // 256 slots x 16 floats
    float* out = (float*)d_out;

    k_normalize<<<N, 256, 0, stream>>>(in, xq, norms, best, psum, D);
    const int T = N / BM;                        // 128 tiles per dim
    const int P = T * (T + 1) / 2;               // 8256 upper-tri blocks
    k_gemm_argmax<<<P, 256, 0, stream>>>(xq, best, T);
    k_dist<<<N, 256, 0, stream>>>(in, norms, best, psum, D);
    k_final<<<1, 64, 0, stream>>>(psum, out, 1.0f / (float)N);
}

// Round 5
// 553.286 us; speedup vs baseline: 4.1035x; 1.5330x over previous
//
#include <hip/hip_runtime.h>

typedef float f32x4 __attribute__((ext_vector_type(4)));
typedef unsigned char uchar;
typedef long i64;

#define KEPS 1e-8f
#define BM 256
#define BN 256
#define BK 64    // fp8 bytes == elements; 16 K-tiles over D=1024

// ---------------- 1) row L2-normalize: fp32 norms + fp8 e4m3 copy -----------
__global__ __launch_bounds__(256) void k_normalize(
    const float* __restrict__ in, uchar* __restrict__ xq,
    float* __restrict__ norms, unsigned long long* __restrict__ best,
    float* __restrict__ psum, int D)
{
    const int row = blockIdx.x;
    const int t = threadIdx.x;
    const float4* inr = (const float4*)(in + (size_t)row * D);
    float4 v = inr[t];                       // D=1024 -> 256 float4
    float ss = v.x*v.x + v.y*v.y + v.z*v.z + v.w*v.w;
    for (int off = 32; off; off >>= 1) ss += __shfl_down(ss, off);
    __shared__ float red[4];
    const int lane = t & 63, wave = t >> 6;
    if (lane == 0) red[wave] = ss;
    __syncthreads();
    const float total = red[0] + red[1] + red[2] + red[3];
    const float nrm = sqrtf(total);
    const float inv = 1.0f / fmaxf(nrm, KEPS);
    unsigned r = 0;
    r = __builtin_amdgcn_cvt_pk_fp8_f32(v.x * inv, v.y * inv, r, 0);
    r = __builtin_amdgcn_cvt_pk_fp8_f32(v.z * inv, v.w * inv, r, 1);
    ((unsigned*)(xq + (size_t)row * D))[t] = r;
    if (t == 0) {
        norms[row] = nrm;
        best[row] = 0ull;                    // any real packed key beats 0
    }
    if (row < 256 && t == 1) psum[row * 16] = 0.0f;   // cache-line-padded partials
}

__device__ __forceinline__ unsigned long long pack_key(float v, unsigned idx)
{
    unsigned ub = __float_as_uint(v);
    ub = (ub & 0x80000000u) ? ~ub : (ub | 0x80000000u); // monotonic map
    return ((unsigned long long)ub << 32) | (unsigned long long)(~idx);
}

// ---------------- 2) x x^T triangular fp8 GEMM: 256^2 deep-pipelined --------
// ROUND-5: MX path abandoned (4 rounds of operand spills; codegen pathology).
// Back to the round-0-proven plain fp8 16x16x32 MFMA (60 VGPR clean), but in
// the 256^2 counted-vmcnt structure (T3+T4+T5) to break the ~36% 2-phase
// ceiling round-0 sat at:
//  - BM=BN=256, BK=64, 8 waves (2Mx4N), per-wave 128x64 out: f32x4 acc[8][4].
//  - Triple-buffered LDS (3 x 32 KiB, dynamic): STAGE for tile kt+3 issued
//    after the end barrier of tile kt; top-of-loop s_waitcnt vmcnt(8) waits
//    ONLY for the current tile's 4 loads (2 younger tiles = 8 stay in
//    flight). vmcnt never drains to 0 in the main loop (T4).
//  - Raw s_barrier + compiler memory fences; setprio(1) around MFMA (T5).
//  - MFMA:ds_read per wave/K-tile = 64:24 (vs 32:16 at 128^2).
// Staging + XOR chunk-swizzle are round-0's verified scheme, scaled: 512
// threads stage 4x16B each (A/B panel halves of 128 rows); swizzle
// chunk16 ^= (row ^ row>>2)&3 applied to the GLOBAL column, LDS stays linear
// (global_load_lds requirement); invariant to row+128 (128%4==0).
// No min-waves launch_bounds (rounds 1-4 lesson: min-waves caps starve the
// unified VGPR file and spill). ~200 regs demand, cap 256 (2 waves/SIMD).
__global__ __launch_bounds__(512) void k_gemm_argmax(
    const uchar* __restrict__ xq, unsigned long long* __restrict__ best,
    int T)
{
    // triangular mapping: p -> (by, bx), bx >= by
    const int p = blockIdx.x;
    const float tf = (float)T + 0.5f;
    int by = (int)(tf - sqrtf(tf * tf - 2.0f * (float)p));
    while (by > 0 && p < by * T - by * (by - 1) / 2) --by;
    while (p >= (by + 1) * T - (by + 1) * by / 2) ++by;
    const int bx = by + (p - (by * T - by * (by - 1) / 2));

    extern __shared__ __align__(1024) uchar lds[];   // 3 x 32768 = 96 KiB
    const int t    = threadIdx.x;                    // 512 threads
    const int lane = t & 63;
    const int wave = t >> 6;                         // 0..7
    const int quad = lane >> 4;
    const int c16  = lane & 15;
    const int wr   = wave >> 2;                      // M-half 0..1
    const int wc   = wave & 3;                       // N-quarter 0..3
    const int m0   = by * BM;
    const int n0   = bx * BN;

    f32x4 acc[8][4] = {};

    // staging: thread t owns 16B chunk c=t of each 128-row half-panel
    // (row_s = t>>2 in [0,128), col chunk = t&3, global col swizzled).
    const int row_s = t >> 2;
    const int col_s = t & 3;
    const int gsw = (col_s ^ ((row_s ^ (row_s >> 2)) & 3)) * 16;  // byte col
    const uchar* aP0 = xq + (size_t)(m0 + row_s) * 1024 + gsw;
    const uchar* bP0 = xq + (size_t)(n0 + row_s) * 1024 + gsw;
    const uchar* aP1 = aP0 + 128 * 1024;
    const uchar* bP1 = bP0 + 128 * 1024;
    const int l16 = t * 16;

#define STAGE(bufbase, koff)                                                              \
    do {                                                                                  \
        __builtin_amdgcn_global_load_lds(                                                 \
            (const __attribute__((address_space(1))) void*)(aP0 + (koff)),                \
            (__attribute__((address_space(3))) void*)(lds + (bufbase) + l16), 16, 0, 0);  \
        __builtin_amdgcn_global_load_lds(                                                 \
            (const __attribute__((address_space(1))) void*)(aP1 + (koff)),                \
            (__attribute__((address_space(3))) void*)(lds + (bufbase) + 8192 + l16), 16, 0, 0); \
        __builtin_amdgcn_global_load_lds(                                                 \
            (const __attribute__((address_space(1))) void*)(bP0 + (koff)),                \
            (__attribute__((address_space(3))) void*)(lds + (bufbase) + 16384 + l16), 16, 0, 0); \
        __builtin_amdgcn_global_load_lds(                                                 \
            (const __attribute__((address_space(1))) void*)(bP1 + (koff)),                \
            (__attribute__((address_space(3))) void*)(lds + (bufbase) + 24576 + l16), 16, 0, 0); \
    } while (0)

    // 3-deep prologue: tiles 0,1,2 in flight (12 loads)
    STAGE(0, 0);
    STAGE(32768, BK);
    STAGE(65536, 2 * BK);

    // lane-constant read offsets. Fragment (fp8 16x16x32): lane holds row
    // c16, k-bytes [quad*8, +8) of the 32B k-slice ks. 16B chunk index
    // cc = ks*2 + (quad>>1), swizzled cc^psw, inner offset (quad&1)*8.
    // psw(row) = (c16 ^ (c16>>2)) & 3 (row = 16*i + c16; multiples of 16
    // drop out of both XOR terms).
    const int psw = (c16 ^ (c16 >> 2)) & 3;
    const int koff0 = (((quad >> 1) ^ psw) * 16) + (quad & 1) * 8;        // ks=0
    const int koff1 = (((2 + (quad >> 1)) ^ psw) * 16) + (quad & 1) * 8;  // ks=1
    const int arow_base = c16 * 64;            // + i*1024 per frag row
    const int brow_base = ((wc & 1) * 64 + c16) * 64;   // + j*1024

    #pragma unroll
    for (int kt = 0; kt < 16; ++kt) {
        // wait for current tile's 4 loads only (8 younger stay in flight)
        if (kt <= 13)      asm volatile("s_waitcnt vmcnt(8)" ::: "memory");
        else if (kt == 14) asm volatile("s_waitcnt vmcnt(4)" ::: "memory");
        else               asm volatile("s_waitcnt vmcnt(0)" ::: "memory");
        __builtin_amdgcn_s_barrier();
        asm volatile("" ::: "memory");

        const uchar* Lb = lds + (kt % 3) * 32768;
        const uchar* Ab = Lb + wr * 8192;                  // this wave's M-half
        const uchar* Bb = Lb + 16384 + (wc >> 1) * 8192;   // this wave's N-half

        __builtin_amdgcn_s_setprio(1);
        #pragma unroll
        for (int ks = 0; ks < 2; ++ks) {
            const int ko = ks ? koff1 : koff0;
            i64 b[4];
            #pragma unroll
            for (int j = 0; j < 4; ++j)
                b[j] = *(const i64*)(Bb + brow_base + j * 1024 + ko);
            #pragma unroll
            for (int i = 0; i < 8; ++i) {
                const i64 a = *(const i64*)(Ab + arow_base + i * 1024 + ko);
                #pragma unroll
                for (int j = 0; j < 4; ++j)
                    acc[i][j] = __builtin_amdgcn_mfma_f32_16x16x32_fp8_fp8(
                        a, b[j], acc[i][j], 0, 0, 0);
            }
        }
        __builtin_amdgcn_s_setprio(0);

        asm volatile("" ::: "memory");
        __builtin_amdgcn_s_barrier();
        asm volatile("" ::: "memory");
        // refill the buffer just consumed with tile kt+3
        if (kt + 3 < 16) STAGE((kt % 3) * 32768, (kt + 3) * BK);
    }
#undef STAGE

    // ---- row-wise argmax (this wave's 128 rows, over its 64 cols) ----
    // C/D layout (16x16, round-0 verified): col = lane&15, row = quad*4 + reg.
    #pragma unroll
    for (int i = 0; i < 8; ++i) {
        #pragma unroll
        for (int r = 0; r < 4; ++r) {
            const int grow = m0 + wr * 128 + i * 16 + quad * 4 + r;
            float v = -3.0f; unsigned c = 0xFFFFFFFFu;
            #pragma unroll
            for (int j = 0; j < 4; ++j) {
                const int col = n0 + wc * 64 + j * 16 + c16;
                const float val = acc[i][j][r];
                if (col != grow && (val > v || (val == v && (unsigned)col < c))) {
                    v = val; c = (unsigned)col;
                }
            }
            // reduce across the quad's 16 lanes (one row lives in one quad)
            for (int off = 8; off; off >>= 1) {
                const float    ov = __shfl_xor(v, off);
                const unsigned oc = (unsigned)__shfl_xor((int)c, off);
                if (ov > v || (ov == v && oc < c)) { v = ov; c = oc; }
            }
            if (c16 == 0) atomicMax(best + grow, pack_key(v, c));
        }
    }

    // ---- col-wise argmax (off-diagonal blocks only) ----
    if (bx != by) {
        #pragma unroll
        for (int j = 0; j < 4; ++j) {
            const int gcol = n0 + wc * 64 + j * 16 + c16;
            float v = -3.0f; unsigned c = 0xFFFFFFFFu;
            #pragma unroll
            for (int i = 0; i < 8; ++i) {
                #pragma unroll
                for (int r = 0; r < 4; ++r) {
                    const int grow = m0 + wr * 128 + i * 16 + quad * 4 + r;
                    const float val = acc[i][j][r];
                    if (val > v || (val == v && (unsigned)grow < c)) {
                        v = val; c = (unsigned)grow;
                    }
                }
            }
            // reduce across the 4 quads (lanes sharing c16): xor 16, 32
            for (int off = 32; off >= 16; off >>= 1) {
                const float    ov = __shfl_xor(v, off);
                const unsigned oc = (unsigned)__shfl_xor((int)c, off);
                if (ov > v || (ov == v && oc < c)) { v = ov; c = oc; }
            }
            if (quad == 0) atomicMax(best + gcol, pack_key(v, c));
        }
    }
}

// ---------------- 3) pairwise distance + log -> 256 padded partials ---------
__global__ __launch_bounds__(256) void k_dist(
    const float* __restrict__ in, const float* __restrict__ norms,
    const unsigned long long* __restrict__ best, float* __restrict__ psum, int D)
{
    const int row = blockIdx.x;
    const int t = threadIdx.x;
    const unsigned long long key = best[row];
    const int nb = (int)(~(unsigned)key);        // recover neighbor index
    const float invi = 1.0f / fmaxf(norms[row], KEPS);
    const float invj = 1.0f / fmaxf(norms[nb], KEPS);
    const float4* xi = (const float4*)(in + (size_t)row * D);
    const float4* xj = (const float4*)(in + (size_t)nb * D);
    const float4 a = xi[t], b = xj[t];
    const float dx = a.x * invi - b.x * invj + KEPS;
    const float dy = a.y * invi - b.y * invj + KEPS;
    const float dz = a.z * invi - b.z * invj + KEPS;
    const float dw = a.w * invi - b.w * invj + KEPS;
    float ss = dx*dx + dy*dy + dz*dz + dw*dw;
    for (int off = 32; off; off >>= 1) ss += __shfl_down(ss, off);
    __shared__ float red[4];
    const int lane = t & 63, wave = t >> 6;
    if (lane == 0) red[wave] = ss;
    __syncthreads();
    if (t == 0) {
        const float tot = red[0] + red[1] + red[2] + red[3];
        // scatter over 256 cache-line-padded slots: 64 atomics/slot, no hotspot
        atomicAdd(psum + (row & 255) * 16, logf(sqrtf(tot) + KEPS));
    }
}

// ---------------- 4) finalize: reduce 256 partials --------------------------
__global__ void k_final(const float* __restrict__ psum, float* __restrict__ out, float invN)
{
    const int t = threadIdx.x;                   // 64 threads
    float s = psum[t * 16] + psum[(t + 64) * 16]
            + psum[(t + 128) * 16] + psum[(t + 192) * 16];
    for (int off = 32; off; off >>= 1) s += __shfl_down(s, off);
    if (t == 0) out[0] = -s * invN;
}

extern "C" void kernel_launch(void* const* d_in, const int* in_sizes, int n_in,
                              void* d_out, int out_size, void* d_ws, size_t ws_size,
                              hipStream_t stream)
{
    const float* in = (const float*)d_in[0];
    const int D = 1024;
    const int N = in_sizes[0] / D;               // 16384

    char* ws = (char*)d_ws;
    uchar* xq = (uchar*)ws;                                      // N*D = 16 MiB
    size_t off = (size_t)N * D;
    float* norms = (float*)(ws + off);           off += (size_t)N * 4;
    unsigned long long* best = (unsigned long long*)(ws + off); off += (size_t)N * 8;
    float* psum = (float*)(ws + off);            // 256 slots x 16 floats
    float* out = (float*)d_out;

    k_normalize<<<N, 256, 0, stream>>>(in, xq, norms, best, psum, D);
    const int T = N / BM;                        // 64 tiles per dim
    const int P = T * (T + 1) / 2;               // 2080 upper-tri blocks
    k_gemm_argmax<<<P, 512, 98304, stream>>>(xq, best, T);
    k_dist<<<N, 256, 0, stream>>>(in, norms, best, psum, D);
    k_final<<<1, 64, 0, stream>>>(psum, out, 1.0f / (float)N);
}

// Round 6
// 432.544 us; speedup vs baseline: 5.2490x; 1.2791x over previous
//
#include <hip/hip_runtime.h>

typedef float f32x4 __attribute__((ext_vector_type(4)));
typedef unsigned char uchar;
typedef long i64;

#define KEPS 1e-8f
#define BM 128
#define BN 128
#define BK 64    // fp8 bytes == elements; 16 K-iterations over D=1024

// ---------------- 1) row L2-normalize: fp32 norms + fp8 e4m3 copy -----------
__global__ __launch_bounds__(256) void k_normalize(
    const float* __restrict__ in, uchar* __restrict__ xq,
    float* __restrict__ norms, unsigned long long* __restrict__ best,
    float* __restrict__ psum, int D)
{
    const int row = blockIdx.x;
    const int t = threadIdx.x;
    const float4* inr = (const float4*)(in + (size_t)row * D);
    float4 v = inr[t];                       // D=1024 -> 256 float4
    float ss = v.x*v.x + v.y*v.y + v.z*v.z + v.w*v.w;
    for (int off = 32; off; off >>= 1) ss += __shfl_down(ss, off);
    __shared__ float red[4];
    const int lane = t & 63, wave = t >> 6;
    if (lane == 0) red[wave] = ss;
    __syncthreads();
    const float total = red[0] + red[1] + red[2] + red[3];
    const float nrm = sqrtf(total);
    const float inv = 1.0f / fmaxf(nrm, KEPS);
    unsigned r = 0;
    r = __builtin_amdgcn_cvt_pk_fp8_f32(v.x * inv, v.y * inv, r, 0);
    r = __builtin_amdgcn_cvt_pk_fp8_f32(v.z * inv, v.w * inv, r, 1);
    ((unsigned*)(xq + (size_t)row * D))[t] = r;
    if (t == 0) {
        norms[row] = nrm;
        best[row] = 0ull;                    // any real packed key beats 0
    }
    if (row < 256 && t == 1) psum[row * 16] = 0.0f;   // cache-line-padded partials
}

__device__ __forceinline__ unsigned long long pack_key(float v, unsigned idx)
{
    unsigned ub = __float_as_uint(v);
    ub = (ub & 0x80000000u) ? ~ub : (ub | 0x80000000u); // monotonic map
    return ((unsigned long long)ub << 32) | (unsigned long long)(~idx);
}

// ---------------- 2) x x^T triangular fp8 GEMM, dbuf LDS, 4 blocks/CU -------
// ROUND-6: revert to the round-0 kernel verbatim (404 µs total / GEMM ~320 µs
// = the proven m97-class 2-phase 128^2 structure; 60 VGPR + 64 AGPR clean).
// Rounds 1-4 (MX-rate mfma_scale) all spilled operand fragments regardless of
// launch_bounds — toolchain codegen pathology. Round 5 (256^2 counted-vmcnt
// pipeline) ran clean but landed at 492 µs (1 block/CU, 2-wave lockstep, LDS
// conflicts on the critical path). Per pre-commitment, structural work stops.
// ONLY change vs round-0: T1 XCD-aware bijective block swizzle (m204 form).
// Mechanism: triangular p->(by,bx) makes consecutive p share the A-panel
// (same by) and walk consecutive B-panels; default dispatch round-robins
// them across 8 non-coherent L2s. Chunked remap gives each XCD a contiguous
// range of the triangle -> A-panel re-reads become same-XCD L2 hits.
__global__ __launch_bounds__(256, 4) void k_gemm_argmax(
    const uchar* __restrict__ xq, unsigned long long* __restrict__ best,
    int T)
{
    // T1: bijective XCD swizzle (hardware: block b lands on XCD b%8)
    const int orig = blockIdx.x;
    const int nwg  = gridDim.x;
    const int q8   = nwg >> 3, r8 = nwg & 7;
    const int xcd  = orig & 7, idx = orig >> 3;
    const int p    = (xcd < r8 ? xcd * (q8 + 1)
                               : r8 * (q8 + 1) + (xcd - r8) * q8) + idx;

    // triangular mapping: p -> (by, bx), bx >= by
    const float tf = (float)T + 0.5f;
    int by = (int)(tf - sqrtf(tf * tf - 2.0f * (float)p));
    while (by > 0 && p < by * T - by * (by - 1) / 2) --by;
    while (p >= (by + 1) * T - (by + 1) * by / 2) ++by;
    const int bx = by + (p - (by * T - by * (by - 1) / 2));

    __shared__ uchar lds[2][(BM + BN) * BK];   // 2 x 16 KiB
    const int t    = threadIdx.x;
    const int lane = t & 63;
    const int wave = t >> 6;
    const int quad = lane >> 4;
    const int c16  = lane & 15;
    const int wrow = (wave >> 1) * 64;
    const int wcol = (wave & 1) * 64;
    const int m0   = by * BM;
    const int n0   = bx * BN;

    f32x4 acc[4][4] = {};

    // staging: thread t owns stored chunk c = t (rows 0..63) and c = t + 256
    // (rows 64..127) of each panel; stored col = t&3, global col swizzled.
    const int row_s = t >> 2;
    const int col_s = t & 3;
    const int gsw = (col_s ^ ((row_s ^ (row_s >> 2)) & 3)) * 16;  // byte col
    // note swz(row+64) == swz(row), so the same gsw serves both halves
    const uchar* aP0 = xq + (size_t)(m0 + row_s) * 1024 + gsw;
    const uchar* bP0 = xq + (size_t)(n0 + row_s) * 1024 + gsw;
    const uchar* aP1 = aP0 + 64 * 1024;
    const uchar* bP1 = bP0 + 64 * 1024;
    const int l16 = t * 16;

#define STAGE(buf, koff)                                                              \
    do {                                                                              \
        __builtin_amdgcn_global_load_lds(                                             \
            (const __attribute__((address_space(1))) void*)(aP0 + (koff)),            \
            (__attribute__((address_space(3))) void*)(&lds[buf][0] + l16), 16, 0, 0); \
        __builtin_amdgcn_global_load_lds(                                             \
            (const __attribute__((address_space(1))) void*)(aP1 + (koff)),            \
            (__attribute__((address_space(3))) void*)(&lds[buf][4096] + l16), 16, 0, 0); \
        __builtin_amdgcn_global_load_lds(                                             \
            (const __attribute__((address_space(1))) void*)(bP0 + (koff)),            \
            (__attribute__((address_space(3))) void*)(&lds[buf][8192] + l16), 16, 0, 0); \
        __builtin_amdgcn_global_load_lds(                                             \
            (const __attribute__((address_space(1))) void*)(bP1 + (koff)),            \
            (__attribute__((address_space(3))) void*)(&lds[buf][12288] + l16), 16, 0, 0); \
    } while (0)

    STAGE(0, 0);
    __syncthreads();

    #pragma unroll
    for (int kt = 0; kt < 16; ++kt) {
        const int cur = kt & 1;
        if (kt < 15) STAGE(cur ^ 1, (kt + 1) * BK);   // K-advance in pointer
        const uchar* Al = &lds[cur][0];
        const uchar* Bl = &lds[cur][8192];
        #pragma unroll
        for (int ks = 0; ks < 2; ++ks) {     // 2 x K=32 per BK=64
            i64 a[4], b[4];
            const int ccol = ks * 2 + (quad >> 1);    // 16B chunk col
            const int inner = (quad & 1) * 8;
            #pragma unroll
            for (int i = 0; i < 4; ++i) {
                const int row = wrow + i * 16 + c16;
                a[i] = *(const i64*)(Al + row * 64 +
                        ((ccol ^ ((row ^ (row >> 2)) & 3)) * 16) + inner);
            }
            #pragma unroll
            for (int j = 0; j < 4; ++j) {
                const int row = wcol + j * 16 + c16;
                b[j] = *(const i64*)(Bl + row * 64 +
                        ((ccol ^ ((row ^ (row >> 2)) & 3)) * 16) + inner);
            }
            #pragma unroll
            for (int i = 0; i < 4; ++i)
                #pragma unroll
                for (int j = 0; j < 4; ++j)
                    acc[i][j] = __builtin_amdgcn_mfma_f32_16x16x32_fp8_fp8(
                        a[i], b[j], acc[i][j], 0, 0, 0);
        }
        __syncthreads();
    }
#undef STAGE

    // ---- row-wise argmax (this wave's 64 rows, over its 64 cols) ----
    // C/D layout (m89-verified, dtype-independent): col = lane&15, row = quad*4 + reg.
    #pragma unroll
    for (int i = 0; i < 4; ++i) {
        #pragma unroll
        for (int r = 0; r < 4; ++r) {
            const int grow = m0 + wrow + i * 16 + quad * 4 + r;
            float v = -3.0f; unsigned c = 0xFFFFFFFFu;
            #pragma unroll
            for (int j = 0; j < 4; ++j) {
                const int col = n0 + wcol + j * 16 + c16;
                const float val = acc[i][j][r];
                if (col != grow && (val > v || (val == v && (unsigned)col < c))) {
                    v = val; c = (unsigned)col;
                }
            }
            // reduce across the quad's 16 lanes (one row lives in one quad)
            for (int off = 8; off; off >>= 1) {
                const float    ov = __shfl_xor(v, off);
                const unsigned oc = (unsigned)__shfl_xor((int)c, off);
                if (ov > v || (ov == v && oc < c)) { v = ov; c = oc; }
            }
            if (c16 == 0) atomicMax(best + grow, pack_key(v, c));
        }
    }

    // ---- col-wise argmax (off-diagonal blocks only) ----
    if (bx != by) {
        #pragma unroll
        for (int j = 0; j < 4; ++j) {
            const int gcol = n0 + wcol + j * 16 + c16;
            float v = -3.0f; unsigned c = 0xFFFFFFFFu;
            #pragma unroll
            for (int i = 0; i < 4; ++i) {
                #pragma unroll
                for (int r = 0; r < 4; ++r) {
                    const int grow = m0 + wrow + i * 16 + quad * 4 + r;
                    const float val = acc[i][j][r];
                    if (val > v || (val == v && (unsigned)grow < c)) {
                        v = val; c = (unsigned)grow;
                    }
                }
            }
            // reduce across the 4 quads (lanes sharing c16): xor 16, 32
            for (int off = 32; off >= 16; off >>= 1) {
                const float    ov = __shfl_xor(v, off);
                const unsigned oc = (unsigned)__shfl_xor((int)c, off);
                if (ov > v || (ov == v && oc < c)) { v = ov; c = oc; }
            }
            if (quad == 0) atomicMax(best + gcol, pack_key(v, c));
        }
    }
}

// ---------------- 3) pairwise distance + log -> 256 padded partials ---------
__global__ __launch_bounds__(256) void k_dist(
    const float* __restrict__ in, const float* __restrict__ norms,
    const unsigned long long* __restrict__ best, float* __restrict__ psum, int D)
{
    const int row = blockIdx.x;
    const int t = threadIdx.x;
    const unsigned long long key = best[row];
    const int nb = (int)(~(unsigned)key);        // recover neighbor index
    const float invi = 1.0f / fmaxf(norms[row], KEPS);
    const float invj = 1.0f / fmaxf(norms[nb], KEPS);
    const float4* xi = (const float4*)(in + (size_t)row * D);
    const float4* xj = (const float4*)(in + (size_t)nb * D);
    const float4 a = xi[t], b = xj[t];
    const float dx = a.x * invi - b.x * invj + KEPS;
    const float dy = a.y * invi - b.y * invj + KEPS;
    const float dz = a.z * invi - b.z * invj + KEPS;
    const float dw = a.w * invi - b.w * invj + KEPS;
    float ss = dx*dx + dy*dy + dz*dz + dw*dw;
    for (int off = 32; off; off >>= 1) ss += __shfl_down(ss, off);
    __shared__ float red[4];
    const int lane = t & 63, wave = t >> 6;
    if (lane == 0) red[wave] = ss;
    __syncthreads();
    if (t == 0) {
        const float tot = red[0] + red[1] + red[2] + red[3];
        // scatter over 256 cache-line-padded slots: 64 atomics/slot, no hotspot
        atomicAdd(psum + (row & 255) * 16, logf(sqrtf(tot) + KEPS));
    }
}

// ---------------- 4) finalize: reduce 256 partials --------------------------
__global__ void k_final(const float* __restrict__ psum, float* __restrict__ out, float invN)
{
    const int t = threadIdx.x;                   // 64 threads
    float s = psum[t * 16] + psum[(t + 64) * 16]
            + psum[(t + 128) * 16] + psum[(t + 192) * 16];
    for (int off = 32; off; off >>= 1) s += __shfl_down(s, off);
    if (t == 0) out[0] = -s * invN;
}

extern "C" void kernel_launch(void* const* d_in, const int* in_sizes, int n_in,
                              void* d_out, int out_size, void* d_ws, size_t ws_size,
                              hipStream_t stream)
{
    const float* in = (const float*)d_in[0];
    const int D = 1024;
    const int N = in_sizes[0] / D;               // 16384

    char* ws = (char*)d_ws;
    uchar* xq = (uchar*)ws;                                      // N*D = 16 MiB
    size_t off = (size_t)N * D;
    float* norms = (float*)(ws + off);           off += (size_t)N * 4;
    unsigned long long* best = (unsigned long long*)(ws + off); off += (size_t)N * 8;
    float* psum = (float*)(ws + off);            // 256 slots x 16 floats
    float* out = (float*)d_out;

    k_normalize<<<N, 256, 0, stream>>>(in, xq, norms, best, psum, D);
    const int T = N / BM;                        // 128 tiles per dim
    const int P = T * (T + 1) / 2;               // 8256 upper-tri blocks
    k_gemm_argmax<<<P, 256, 0, stream>>>(xq, best, T);
    k_dist<<<N, 256, 0, stream>>>(in, norms, best, psum, D);
    k_final<<<1, 64, 0, stream>>>(psum, out, 1.0f / (float)N);
}